// Round 1
// baseline (2887.808 us; speedup 1.0000x reference)
//
#include <hip/hip_runtime.h>
#include <hip/hip_bf16.h>
#include <cstdint>

// Problem constants (B=8, S=1024, C=2048, V=50257)
#define N_ROWS 8192
#define CDIM   2048
#define VDIM   50257
#define BM     128
#define BN     128
#define BK     32
#define VTILES 393              // ceil(VDIM / BN)
#define KT_ITERS (CDIM / BK)    // 64

static_assert(VTILES == (VDIM + BN - 1) / BN, "vtile count");

using short8 = __attribute__((ext_vector_type(8))) short;
using u16x8  = __attribute__((ext_vector_type(8))) unsigned short;
using f32x4  = __attribute__((ext_vector_type(4))) float;

// ---------- fp32 -> bf16 (RNE) ----------
__device__ __forceinline__ unsigned short f2bf(float f) {
    unsigned int u = __float_as_uint(f);
    u += 0x7FFFu + ((u >> 16) & 1u);
    return (unsigned short)(u >> 16);
}

__global__ __launch_bounds__(256) void cvt_bf16_kernel(const float* __restrict__ in,
                                                       unsigned short* __restrict__ out,
                                                       long n8) {
    long stride = (long)gridDim.x * blockDim.x;
    for (long i = (long)blockIdx.x * blockDim.x + threadIdx.x; i < n8; i += stride) {
        const float4* p = (const float4*)in + 2 * i;
        float4 a = p[0];
        float4 b = p[1];
        u16x8 v;
        v[0] = f2bf(a.x); v[1] = f2bf(a.y); v[2] = f2bf(a.z); v[3] = f2bf(a.w);
        v[4] = f2bf(b.x); v[5] = f2bf(b.y); v[6] = f2bf(b.z); v[7] = f2bf(b.w);
        ((u16x8*)out)[i] = v;
    }
}

// ---------- slot permutation for LDS bank-conflict-free ds_read_b128 ----------
// Row r (64B of bf16 per row at BK=32) has 4 16B slots. perm spreads the 16
// rows a fragment-read touches across banks so the wave read is 2-way (free).
__device__ __forceinline__ int slot_perm(int r) { return (r ^ (r >> 1)) & 3; }

__device__ __forceinline__ void gload_lds16(const void* g, void* l) {
    __builtin_amdgcn_global_load_lds(
        (const __attribute__((address_space(1))) unsigned int*)g,
        (__attribute__((address_space(3))) unsigned int*)l, 16, 0, 0);
}

// ---------- fused GEMM + per-(row, vtile) sum of exp(logit) ----------
// logits[r][v] = sum_k x[r][k] * W[v][k]  (+ bias[v] in epilogue)
// A = x_bf16 (row-major, K contiguous), B = W_bf16 (row-major, K contiguous).
__global__ __launch_bounds__(256) void gemm_lse_kernel(const unsigned short* __restrict__ Xb,
                                                       const unsigned short* __restrict__ Wb,
                                                       const float* __restrict__ bias,
                                                       float* __restrict__ partials) {
    // XCD-aware bijective swizzle (gridDim.x = 25152, divisible by 8):
    // each XCD gets a contiguous chunk; row-tile fastest so co-resident
    // blocks share the same W panel in the XCD's L2.
    int bid = blockIdx.x;
    int cpx = gridDim.x >> 3;
    int wg  = (bid & 7) * cpx + (bid >> 3);
    int rt  = wg & 63;          // 64 row tiles
    int vt  = wg >> 6;          // 393 vocab tiles
    int row0 = rt * BM;
    int v0   = vt * BN;

    __shared__ unsigned short Abuf[BM * BK];   // 8 KiB
    __shared__ unsigned short Bbuf[BN * BK];   // 8 KiB
    __shared__ float ps[2][BM];

    const int t  = threadIdx.x;
    const int w  = t >> 6;
    const int l  = t & 63;
    const int wr = w >> 1;      // wave row (0..1): rows wr*64..+63
    const int wc = w & 1;       // wave col (0..1): cols wc*64..+63
    const int g  = l >> 4;      // k-group 0..3 (8 bf16 each)
    const int lr = l & 15;

    // staging chunk decomposition (16B chunks, lane-linear LDS dest):
    // chunk c: row = c>>2, physical slot = c&3, logical slot = phys ^ perm(row)
    int sr[2], sk[2];
    #pragma unroll
    for (int i = 0; i < 2; ++i) {
        int c = t + i * 256;
        sr[i] = c >> 2;
        sk[i] = (c & 3) ^ slot_perm(c >> 2);   // logical k-slot to fetch
    }
    int bvrow[2];
    #pragma unroll
    for (int i = 0; i < 2; ++i) {
        int vr = v0 + sr[i];
        bvrow[i] = (vr < VDIM) ? vr : (VDIM - 1);   // clamp; masked in epilogue
    }

    f32x4 acc[4][4];
    #pragma unroll
    for (int m = 0; m < 4; ++m)
        #pragma unroll
        for (int n = 0; n < 4; ++n)
            acc[m][n] = (f32x4)0.0f;

    const int arow_slot = slot_perm((wr * 64 + lr) & 15);  // perm depends on row&3 bits only... recompute exactly below

    for (int kt = 0; kt < KT_ITERS; ++kt) {
        const int k0 = kt * BK;
        // ---- stage A and B tiles (global_load_lds, 16B, pre-swizzled source)
        #pragma unroll
        for (int i = 0; i < 2; ++i) {
            int c = t + i * 256;
            gload_lds16(Xb + (size_t)(row0 + sr[i]) * CDIM + k0 + sk[i] * 8,
                        &Abuf[c * 8]);
        }
        #pragma unroll
        for (int i = 0; i < 2; ++i) {
            int c = t + i * 256;
            gload_lds16(Wb + (size_t)bvrow[i] * CDIM + k0 + sk[i] * 8,
                        &Bbuf[c * 8]);
        }
        __syncthreads();   // drains vmcnt -> staged data visible

        // ---- fragments (swizzled read: phys slot = g ^ perm(row))
        short8 af[4], bfr[4];
        #pragma unroll
        for (int m = 0; m < 4; ++m) {
            int row = wr * 64 + m * 16 + lr;
            int sp  = g ^ slot_perm(row);
            af[m] = *(const short8*)&Abuf[row * BK + sp * 8];
        }
        #pragma unroll
        for (int n = 0; n < 4; ++n) {
            int row = wc * 64 + n * 16 + lr;
            int sp  = g ^ slot_perm(row);
            bfr[n] = *(const short8*)&Bbuf[row * BK + sp * 8];
        }
        #pragma unroll
        for (int m = 0; m < 4; ++m)
            #pragma unroll
            for (int n = 0; n < 4; ++n)
                acc[m][n] = __builtin_amdgcn_mfma_f32_16x16x32_bf16(
                    af[m], bfr[n], acc[m][n], 0, 0, 0);
        __syncthreads();   // before next stage overwrites
    }

    // ---- epilogue: per-row sum of exp(logit + bias) over this tile's 128 cols
    // C/D layout (16x16x32): col = lane&15, row = (lane>>4)*4 + reg.
    float bvals[4];
    bool  valid[4];
    #pragma unroll
    for (int n = 0; n < 4; ++n) {
        int v = v0 + wc * 64 + n * 16 + lr;
        valid[n] = (v < VDIM);
        bvals[n] = valid[n] ? bias[v] : 0.0f;
    }
    #pragma unroll
    for (int m = 0; m < 4; ++m) {
        #pragma unroll
        for (int i = 0; i < 4; ++i) {
            float s = 0.0f;
            #pragma unroll
            for (int n = 0; n < 4; ++n) {
                float e = valid[n] ? __expf(acc[m][n][i] + bvals[n]) : 0.0f;
                s += e;
            }
            // reduce across the 16 lanes holding this row (masks <16 stay in-group)
            s += __shfl_xor(s, 1);
            s += __shfl_xor(s, 2);
            s += __shfl_xor(s, 4);
            s += __shfl_xor(s, 8);
            if (lr == 0) ps[wc][wr * 64 + m * 16 + g * 4 + i] = s;
        }
    }
    __syncthreads();
    if (t < BM) {
        float s = ps[0][t] + ps[1][t];
        partials[(size_t)(row0 + t) * VTILES + vt] = s;
    }
}

// ---------- exact fp32 target logit: tgt[r] = dot(x[r], W[y[r]]) + b[y[r]] ----------
__global__ __launch_bounds__(256) void tgt_kernel(const float* __restrict__ x,
                                                  const float* __restrict__ W,
                                                  const float* __restrict__ bias,
                                                  const int* __restrict__ y,
                                                  float* __restrict__ tgt) {
    int row = blockIdx.x * 4 + (threadIdx.x >> 6);
    int l   = threadIdx.x & 63;
    int yv  = y[row];
    const float4* xr = (const float4*)(x + (size_t)row * CDIM);
    const float4* wr = (const float4*)(W + (size_t)yv * CDIM);
    float s = 0.0f;
    #pragma unroll
    for (int i = l; i < CDIM / 4; i += 64) {
        float4 a = xr[i];
        float4 b = wr[i];
        s += a.x * b.x + a.y * b.y + a.z * b.z + a.w * b.w;
    }
    #pragma unroll
    for (int off = 32; off > 0; off >>= 1) s += __shfl_down(s, off);
    if (l == 0) tgt[row] = s + bias[yv];
}

// ---------- per-row: loss = log(sum over vtiles) - tgt; atomic accumulate ----------
__global__ __launch_bounds__(256) void reduce_kernel(const float* __restrict__ partials,
                                                     const float* __restrict__ tgt,
                                                     float* __restrict__ acc) {
    int row = blockIdx.x * 4 + (threadIdx.x >> 6);
    int l   = threadIdx.x & 63;
    const float* p = partials + (size_t)row * VTILES;
    float s = 0.0f;
    for (int i = l; i < VTILES; i += 64) s += p[i];
    #pragma unroll
    for (int off = 32; off > 0; off >>= 1) s += __shfl_down(s, off);
    if (l == 0) {
        float loss = logf(s) - tgt[row];
        atomicAdd(acc, loss);
    }
}

__global__ void finalize_kernel(const float* __restrict__ acc, float* __restrict__ out) {
    if (threadIdx.x == 0) out[0] = acc[0] * (1.0f / (float)N_ROWS);
}

extern "C" void kernel_launch(void* const* d_in, const int* in_sizes, int n_in,
                              void* d_out, int out_size, void* d_ws, size_t ws_size,
                              hipStream_t stream) {
    const float* x    = (const float*)d_in[0];   // [8192, 2048] f32
    const int*   y    = (const int*)d_in[1];     // [8192] int
    const float* W    = (const float*)d_in[2];   // [50257, 2048] f32
    const float* bias = (const float*)d_in[3];   // [50257] f32
    float* out = (float*)d_out;

    // workspace layout (bytes)
    const size_t W_BYTES = (size_t)VDIM * CDIM * 2;      // 205,852,672
    const size_t X_BYTES = (size_t)N_ROWS * CDIM * 2;    //  33,554,432
    const size_t P_BYTES = (size_t)N_ROWS * VTILES * 4;  //  12,877,824
    const size_t T_BYTES = (size_t)N_ROWS * 4;           //      32,768
    char* ws = (char*)d_ws;
    unsigned short* Wb = (unsigned short*)ws;
    unsigned short* Xb = (unsigned short*)(ws + W_BYTES);
    float* partials    = (float*)(ws + W_BYTES + X_BYTES);
    float* tgt         = (float*)(ws + W_BYTES + X_BYTES + P_BYTES);
    float* acc         = (float*)(ws + W_BYTES + X_BYTES + P_BYTES + T_BYTES);

    cvt_bf16_kernel<<<2048, 256, 0, stream>>>(W, Wb, (long)VDIM * CDIM / 8);
    cvt_bf16_kernel<<<2048, 256, 0, stream>>>(x, Xb, (long)N_ROWS * CDIM / 8);
    hipMemsetAsync(acc, 0, 4, stream);

    gemm_lse_kernel<<<64 * VTILES, 256, 0, stream>>>(Xb, Wb, bias, partials);
    tgt_kernel<<<N_ROWS / 4, 256, 0, stream>>>(x, W, bias, y, tgt);
    reduce_kernel<<<N_ROWS / 4, 256, 0, stream>>>(partials, tgt, acc);
    finalize_kernel<<<1, 64, 0, stream>>>(acc, out);
}

// Round 2
// 2805.250 us; speedup vs baseline: 1.0294x; 1.0294x over previous
//
#include <hip/hip_runtime.h>
#include <hip/hip_bf16.h>
#include <cstdint>

// Problem constants (B=8, S=1024, C=2048, V=50257)
#define N_ROWS 8192
#define CDIM   2048
#define VDIM   50257
#define BM     256
#define BN     256
#define BK     64
#define VTILES 197              // ceil(VDIM / 256)
#define KTILES (CDIM / BK)      // 32

static_assert(VTILES == (VDIM + BN - 1) / BN, "vtile count");

using short8 = __attribute__((ext_vector_type(8))) short;
using u16x8  = __attribute__((ext_vector_type(8))) unsigned short;
using f32x4  = __attribute__((ext_vector_type(4))) float;

// ---------- fp32 -> bf16 (RNE) ----------
__device__ __forceinline__ unsigned short f2bf(float f) {
    unsigned int u = __float_as_uint(f);
    u += 0x7FFFu + ((u >> 16) & 1u);
    return (unsigned short)(u >> 16);
}

__global__ __launch_bounds__(256) void cvt_bf16_kernel(const float* __restrict__ in,
                                                       unsigned short* __restrict__ out,
                                                       long n8) {
    long stride = (long)gridDim.x * blockDim.x;
    for (long i = (long)blockIdx.x * blockDim.x + threadIdx.x; i < n8; i += stride) {
        const float4* p = (const float4*)in + 2 * i;
        float4 a = p[0];
        float4 b = p[1];
        u16x8 v;
        v[0] = f2bf(a.x); v[1] = f2bf(a.y); v[2] = f2bf(a.z); v[3] = f2bf(a.w);
        v[4] = f2bf(b.x); v[5] = f2bf(b.y); v[6] = f2bf(b.z); v[7] = f2bf(b.w);
        ((u16x8*)out)[i] = v;
    }
}

__device__ __forceinline__ void gload_lds16(const void* g, void* l) {
    __builtin_amdgcn_global_load_lds(
        (const __attribute__((address_space(1))) unsigned int*)g,
        (__attribute__((address_space(3))) unsigned int*)l, 16, 0, 0);
}

// ---------- fused 256x256 8-phase GEMM + per-(row, vtile) sum of exp ----------
// logits[r][v] = sum_k x[r][k]*W[v][k] + b[v];  partials[r][vt] = sum_v exp(logit)
__global__ __launch_bounds__(512, 2) void gemm_lse_kernel(const unsigned short* __restrict__ Xb,
                                                          const unsigned short* __restrict__ Wb,
                                                          const float* __restrict__ bias,
                                                          float* __restrict__ partials) {
    // LDS: A,B double-buffered [2][256][64] bf16 each (64 KiB each) + ps (4 KiB)
    __shared__ unsigned short Alds[2][256][64];
    __shared__ unsigned short Blds[2][256][64];
    __shared__ float psm[4 * 256];

    // XCD-aware bijective swizzle (grid = 6304, divisible by 8). Row-tile
    // fastest inside an XCD chunk -> co-resident blocks share the W panel in L2.
    int bid = blockIdx.x;
    int cpx = gridDim.x >> 3;
    int wg  = (bid & 7) * cpx + (bid >> 3);
    int rt  = wg & 31;          // 32 row tiles
    int vt  = wg >> 5;          // 197 vocab tiles
    int row0 = rt * BM;
    int v0   = vt * BN;

    const int t  = threadIdx.x;
    const int l  = t & 63;
    const int w  = t >> 6;
    const int wr = w >> 2;      // 0..1 : rows wr*128..+128
    const int wc = w & 3;       // 0..3 : cols wc*64..+64
    const int g  = l >> 4;      // k-group 0..3
    const int lr = l & 15;

    // ---- read-side addressing (byte offsets; XOR swizzle (row&7)<<4) ----
    const int xorm  = (lr & 7) << 4;
    const int colk0 = (g * 16) ^ xorm;          // ks=0
    const int colk1 = (64 + g * 16) ^ xorm;     // ks=1
    const int rbA   = wr * 16384 + lr * 128;
    const int rbB   = wc * 8192  + lr * 128;

    // ---- stage-side addressing (linear LDS dest, inverse-swizzled source) ----
    const int rl = t >> 3;                       // row-in-half 0..63 (chunk i adds 64)
    const int sl = (t & 7) ^ (rl & 7);           // swizzled k-slot (same for both chunks)
    const unsigned short* pA00 = Xb + (size_t)(row0 +       rl     ) * CDIM + sl * 8;
    const unsigned short* pA01 = Xb + (size_t)(row0 +       rl + 64) * CDIM + sl * 8;
    const unsigned short* pA10 = Xb + (size_t)(row0 + 128 + rl     ) * CDIM + sl * 8;
    const unsigned short* pA11 = Xb + (size_t)(row0 + 128 + rl + 64) * CDIM + sl * 8;
    auto brow = [&](int r) -> size_t {
        int v = v0 + r;
        return (size_t)(v < VDIM ? v : VDIM - 1);   // clamp; masked in epilogue
    };
    const unsigned short* pB00 = Wb + brow(      rl     ) * CDIM + sl * 8;
    const unsigned short* pB01 = Wb + brow(      rl + 64) * CDIM + sl * 8;
    const unsigned short* pB10 = Wb + brow(128 + rl     ) * CDIM + sl * 8;
    const unsigned short* pB11 = Wb + brow(128 + rl + 64) * CDIM + sl * 8;

    char* AlBase = (char*)&Alds[0][0][0];
    char* BlBase = (char*)&Blds[0][0][0];
    const int dst0 = t * 16;

#define STAGE2(P0, P1, DB) do { \
        gload_lds16((P0), (DB) + dst0); \
        gload_lds16((P1), (DB) + dst0 + 8192); \
    } while (0)

    // ---- prologue: A(0), B(0), B(1); leave B(1) (4 loads/thread) in flight ----
    STAGE2(pA00, pA01, AlBase);                     // A(0) half0 -> buf0
    STAGE2(pA10, pA11, AlBase + 16384);             // A(0) half1
    STAGE2(pB00, pB01, BlBase);                     // B(0) half0 -> buf0
    STAGE2(pB10, pB11, BlBase + 16384);             // B(0) half1
    STAGE2(pB00 + 64, pB01 + 64, BlBase + 32768);           // B(1) half0 -> buf1
    STAGE2(pB10 + 64, pB11 + 64, BlBase + 32768 + 16384);   // B(1) half1
    pA00 += 64;  pA01 += 64;  pA10 += 64;  pA11 += 64;      // -> K-tile 1
    pB00 += 128; pB01 += 128; pB10 += 128; pB11 += 128;     // -> K-tile 2
    asm volatile("s_waitcnt vmcnt(4)" ::: "memory");        // A(0)+B(0) landed
    __builtin_amdgcn_s_barrier();

    f32x4 acc[8][4];
    #pragma unroll
    for (int m = 0; m < 8; ++m)
        #pragma unroll
        for (int n = 0; n < 4; ++n)
            acc[m][n] = (f32x4)0.0f;

    short8 af[2][4], bf[2][4];

    for (int kt = 0; kt < KTILES; ++kt) {
        const char* Ab = AlBase + (kt & 1) * 32768;   // compute buffers
        const char* Bb = BlBase + (kt & 1) * 32768;
        char* An = AlBase + ((kt + 1) & 1) * 32768;   // A(kt+1) dest
        char* Bn = BlBase + (kt & 1) * 32768;         // B(kt+2) dest (== Bb; safe: B reads end at q1)

        // ---- q0: read A(mh0)+B(nh0), stage A(kt+1) h0, MFMA (mh0,nh0) ----
        #pragma unroll
        for (int ks = 0; ks < 2; ++ks) {
            const int ck = ks ? colk1 : colk0;
            #pragma unroll
            for (int mm = 0; mm < 4; ++mm)
                af[ks][mm] = *(const short8*)(Ab + rbA + mm * 2048 + ck);
            #pragma unroll
            for (int nn = 0; nn < 2; ++nn)
                bf[ks][nn] = *(const short8*)(Bb + rbB + nn * 2048 + ck);
        }
        STAGE2(pA00, pA01, An);
        __builtin_amdgcn_s_barrier();
        __builtin_amdgcn_s_setprio(1);
        #pragma unroll
        for (int ks = 0; ks < 2; ++ks)
            #pragma unroll
            for (int mm = 0; mm < 4; ++mm)
                #pragma unroll
                for (int nn = 0; nn < 2; ++nn)
                    acc[mm][nn] = __builtin_amdgcn_mfma_f32_16x16x32_bf16(
                        af[ks][mm], bf[ks][nn], acc[mm][nn], 0, 0, 0);
        __builtin_amdgcn_s_setprio(0);
        __builtin_amdgcn_s_barrier();

        // ---- q1: read B(nh1), stage A(kt+1) h1, MFMA (mh0,nh1) ----
        #pragma unroll
        for (int ks = 0; ks < 2; ++ks) {
            const int ck = ks ? colk1 : colk0;
            #pragma unroll
            for (int nn = 0; nn < 2; ++nn)
                bf[ks][2 + nn] = *(const short8*)(Bb + rbB + (2 + nn) * 2048 + ck);
        }
        STAGE2(pA10, pA11, An + 16384);
        __builtin_amdgcn_s_barrier();
        __builtin_amdgcn_s_setprio(1);
        #pragma unroll
        for (int ks = 0; ks < 2; ++ks)
            #pragma unroll
            for (int mm = 0; mm < 4; ++mm)
                #pragma unroll
                for (int nn = 0; nn < 2; ++nn)
                    acc[mm][2 + nn] = __builtin_amdgcn_mfma_f32_16x16x32_bf16(
                        af[ks][mm], bf[ks][2 + nn], acc[mm][2 + nn], 0, 0, 0);
        __builtin_amdgcn_s_setprio(0);
        __builtin_amdgcn_s_barrier();

        // ---- q2: read A(mh1) (overwrite af), stage B(kt+2) h0, MFMA (mh1,nh1) ----
        #pragma unroll
        for (int ks = 0; ks < 2; ++ks) {
            const int ck = ks ? colk1 : colk0;
            #pragma unroll
            for (int mm = 0; mm < 4; ++mm)
                af[ks][mm] = *(const short8*)(Ab + rbA + 8192 + mm * 2048 + ck);
        }
        STAGE2(pB00, pB01, Bn);
        __builtin_amdgcn_s_barrier();
        __builtin_amdgcn_s_setprio(1);
        #pragma unroll
        for (int ks = 0; ks < 2; ++ks)
            #pragma unroll
            for (int mm = 0; mm < 4; ++mm)
                #pragma unroll
                for (int nn = 0; nn < 2; ++nn)
                    acc[4 + mm][2 + nn] = __builtin_amdgcn_mfma_f32_16x16x32_bf16(
                        af[ks][mm], bf[ks][2 + nn], acc[4 + mm][2 + nn], 0, 0, 0);
        __builtin_amdgcn_s_setprio(0);
        __builtin_amdgcn_s_barrier();

        // ---- q3: stage B(kt+2) h1, MFMA (mh1,nh0), boundary vmcnt(4) ----
        STAGE2(pB10, pB11, Bn + 16384);
        __builtin_amdgcn_s_barrier();
        __builtin_amdgcn_s_setprio(1);
        #pragma unroll
        for (int ks = 0; ks < 2; ++ks)
            #pragma unroll
            for (int mm = 0; mm < 4; ++mm)
                #pragma unroll
                for (int nn = 0; nn < 2; ++nn)
                    acc[4 + mm][nn] = __builtin_amdgcn_mfma_f32_16x16x32_bf16(
                        af[ks][mm], bf[ks][nn], acc[4 + mm][nn], 0, 0, 0);
        __builtin_amdgcn_s_setprio(0);
        pA00 += 64; pA01 += 64; pA10 += 64; pA11 += 64;
        pB00 += 64; pB01 += 64; pB10 += 64; pB11 += 64;
        // retire everything except the newest 4 loads (B(kt+2)) -> A(kt+1),B(kt+1) landed
        asm volatile("s_waitcnt vmcnt(4)" ::: "memory");
        __builtin_amdgcn_s_barrier();
    }

    asm volatile("s_waitcnt vmcnt(0)" ::: "memory");   // drain tail stages

    // ---- epilogue: per-row sum of exp(logit + bias) over this tile's 256 cols
    // C/D layout: col = lane&15, row = (lane>>4)*4 + reg.
    float bvals[4];
    bool  valid[4];
    #pragma unroll
    for (int nn = 0; nn < 4; ++nn) {
        int v = v0 + wc * 64 + nn * 16 + lr;
        valid[nn] = (v < VDIM);
        bvals[nn] = bias[valid[nn] ? v : 0];
    }
    #pragma unroll
    for (int mm = 0; mm < 8; ++mm) {
        #pragma unroll
        for (int i = 0; i < 4; ++i) {
            float s = 0.0f;
            #pragma unroll
            for (int nn = 0; nn < 4; ++nn)
                s += valid[nn] ? __expf(acc[mm][nn][i] + bvals[nn]) : 0.0f;
            s += __shfl_xor(s, 1);
            s += __shfl_xor(s, 2);
            s += __shfl_xor(s, 4);
            s += __shfl_xor(s, 8);
            if (lr == 0) psm[wc * 256 + wr * 128 + mm * 16 + g * 4 + i] = s;
        }
    }
    __syncthreads();
    if (t < 256) {
        float s = psm[t] + psm[256 + t] + psm[512 + t] + psm[768 + t];
        partials[(size_t)(row0 + t) * VTILES + vt] = s;
    }
#undef STAGE2
}

// ---------- exact fp32 target logit: tgt[r] = dot(x[r], W[y[r]]) + b[y[r]] ----------
__global__ __launch_bounds__(256) void tgt_kernel(const float* __restrict__ x,
                                                  const float* __restrict__ W,
                                                  const float* __restrict__ bias,
                                                  const int* __restrict__ y,
                                                  float* __restrict__ tgt) {
    int row = blockIdx.x * 4 + (threadIdx.x >> 6);
    int l   = threadIdx.x & 63;
    int yv  = y[row];
    const float4* xr = (const float4*)(x + (size_t)row * CDIM);
    const float4* wr = (const float4*)(W + (size_t)yv * CDIM);
    float s = 0.0f;
    #pragma unroll
    for (int i = l; i < CDIM / 4; i += 64) {
        float4 a = xr[i];
        float4 b = wr[i];
        s += a.x * b.x + a.y * b.y + a.z * b.z + a.w * b.w;
    }
    #pragma unroll
    for (int off = 32; off > 0; off >>= 1) s += __shfl_down(s, off);
    if (l == 0) tgt[row] = s + bias[yv];
}

// ---------- per-row: loss = log(sum over vtiles) - tgt; atomic accumulate ----------
__global__ __launch_bounds__(256) void reduce_kernel(const float* __restrict__ partials,
                                                     const float* __restrict__ tgt,
                                                     float* __restrict__ acc) {
    int row = blockIdx.x * 4 + (threadIdx.x >> 6);
    int l   = threadIdx.x & 63;
    const float* p = partials + (size_t)row * VTILES;
    float s = 0.0f;
    for (int i = l; i < VTILES; i += 64) s += p[i];
    #pragma unroll
    for (int off = 32; off > 0; off >>= 1) s += __shfl_down(s, off);
    if (l == 0) {
        float loss = logf(s) - tgt[row];
        atomicAdd(acc, loss);
    }
}

__global__ void finalize_kernel(const float* __restrict__ acc, float* __restrict__ out) {
    if (threadIdx.x == 0) out[0] = acc[0] * (1.0f / (float)N_ROWS);
}

extern "C" void kernel_launch(void* const* d_in, const int* in_sizes, int n_in,
                              void* d_out, int out_size, void* d_ws, size_t ws_size,
                              hipStream_t stream) {
    const float* x    = (const float*)d_in[0];   // [8192, 2048] f32
    const int*   y    = (const int*)d_in[1];     // [8192] int
    const float* W    = (const float*)d_in[2];   // [50257, 2048] f32
    const float* bias = (const float*)d_in[3];   // [50257] f32
    float* out = (float*)d_out;

    // workspace layout (bytes)
    const size_t W_BYTES = (size_t)VDIM * CDIM * 2;      // 205,852,672
    const size_t X_BYTES = (size_t)N_ROWS * CDIM * 2;    //  33,554,432
    const size_t P_BYTES = (size_t)N_ROWS * VTILES * 4;  //   6,455,296
    const size_t T_BYTES = (size_t)N_ROWS * 4;
    char* ws = (char*)d_ws;
    unsigned short* Wb = (unsigned short*)ws;
    unsigned short* Xb = (unsigned short*)(ws + W_BYTES);
    float* partials    = (float*)(ws + W_BYTES + X_BYTES);
    float* tgt         = (float*)(ws + W_BYTES + X_BYTES + P_BYTES);
    float* acc         = (float*)(ws + W_BYTES + X_BYTES + P_BYTES + T_BYTES);

    cvt_bf16_kernel<<<4096, 256, 0, stream>>>(W, Wb, (long)VDIM * CDIM / 8);
    cvt_bf16_kernel<<<2048, 256, 0, stream>>>(x, Xb, (long)N_ROWS * CDIM / 8);
    hipMemsetAsync(acc, 0, 4, stream);

    gemm_lse_kernel<<<32 * VTILES, 512, 0, stream>>>(Xb, Wb, bias, partials);
    tgt_kernel<<<N_ROWS / 4, 256, 0, stream>>>(x, W, bias, y, tgt);
    reduce_kernel<<<N_ROWS / 4, 256, 0, stream>>>(partials, tgt, acc);
    finalize_kernel<<<1, 64, 0, stream>>>(acc, out);
}